// Round 1
// 99.038 us; speedup vs baseline: 1.0134x; 1.0134x over previous
//
#include <hip/hip_runtime.h>

#define NB 4
#define DD 128
#define NN 4096
#define INV_T 14.285714285714285f
// INV_T * log2(e) : exp(x/T) == exp2(x * EXP2C)
#define EXP2C 20.60992915555662f

typedef __attribute__((ext_vector_type(8))) short bf16x8;
typedef __attribute__((ext_vector_type(4))) float f32x4;

static __device__ __forceinline__ unsigned short f32_to_bf16(float x){
  unsigned u = __float_as_uint(x);
  u += 0x7fffu + ((u >> 16) & 1u);   // RNE
  return (unsigned short)(u >> 16);
}

// async 16B global->LDS DMA (lds dest must be wave-uniform; lands at +lane*16)
static __device__ __forceinline__ void async_copy16(const uint4* g, uint4* l){
  __builtin_amdgcn_global_load_lds(
      (const __attribute__((address_space(1))) unsigned int*)g,
      (__attribute__((address_space(3))) unsigned int*)l, 16, 0, 0);
}

// Kernel A: L1-normalize + transpose [B][128][N] fp32 -> [B][N][128] bf16
// 16B chunks stored XOR-swizzled within each row: true chunk c of row r lands
// at slot c ^ (r&15), so a *linear* global_load_lds copy in simexp produces the
// bank-conflict-free swizzled LDS layout directly.
// Also zeroes rowsum/out (replaces two hipMemsetAsync dispatches).
__global__ __launch_bounds__(256) void norm_kernel(const float* __restrict__ fq,
                                                   const float* __restrict__ fk,
                                                   unsigned short* __restrict__ qn,
                                                   unsigned short* __restrict__ kn,
                                                   float* __restrict__ rowsum,
                                                   float* __restrict__ out){
  const float* src = blockIdx.z ? fk : fq;
  unsigned short* dst = blockIdx.z ? kn : qn;
  int b = blockIdx.y;
  int n0 = blockIdx.x * 64;
  int t = threadIdx.x;
  // fold the memsets into this (first) kernel: z==0 blocks cover all 16384 rows
  if (blockIdx.z == 0 && t < 64) rowsum[b*NN + n0 + t] = 0.f;
  if (blockIdx.z == 0 && blockIdx.x == 0 && b == 0 && t == 64) *out = 0.f;
  __shared__ float sT[64][129];   // stride 129: conflict-free col writes/row reads
  __shared__ float red[4][64];
  __shared__ float srd[64];
  const float* sb = src + (size_t)b*DD*NN + n0;
  // vectorized staging: float4 per lane (16B), 1KB per wave instruction
  #pragma unroll
  for (int it = 0; it < 8; ++it){
    int idx = it*256 + t;           // 0..2047
    int d = idx >> 4, g = idx & 15; // row d, float4 group g
    const float4 v = *reinterpret_cast<const float4*>(sb + (size_t)d*NN + g*4);
    sT[g*4+0][d] = v.x;
    sT[g*4+1][d] = v.y;
    sT[g*4+2][d] = v.z;
    sT[g*4+3][d] = v.w;
  }
  __syncthreads();
  {
    int nn = t & 63, part = t >> 6;
    float s = 0.f;
    #pragma unroll
    for (int j = 0; j < 32; ++j) s += fabsf(sT[nn][part*32 + j]);
    red[part][nn] = s;
  }
  __syncthreads();
  if (t < 64){
    float dsum = red[0][t] + red[1][t] + red[2][t] + red[3][t];
    srd[t] = 1.f / fmaxf(dsum, 1e-12f);
  }
  __syncthreads();
  unsigned short* db = dst + ((size_t)b*NN + n0)*DD;
  #pragma unroll
  for (int it = 0; it < 4; ++it){
    int c = it*256 + t;
    int row = c >> 4, dc = c & 15;
    float r = srd[row];
    unsigned v[4];
    #pragma unroll
    for (int p = 0; p < 4; ++p){
      unsigned short lo = f32_to_bf16(sT[row][dc*8 + p*2    ] * r);
      unsigned short hi = f32_to_bf16(sT[row][dc*8 + p*2 + 1] * r);
      v[p] = (unsigned)lo | ((unsigned)hi << 16);
    }
    uint4 pack = make_uint4(v[0], v[1], v[2], v[3]);
    int sw = dc ^ (row & 15);     // global pre-swizzle (row & 15 == global row & 15)
    *reinterpret_cast<uint4*>(db + (size_t)row*DD + sw*8) = pack;
  }
}

// Kernel B: sim = qn . kn^T tilewise (bf16 MFMA), rowsum += sum_cols exp2(sim*EXP2C)
// block tile 128 rows x 1024 cols (8 k-tiles of 128), grid (32, 4, B)
// Double-buffered K staging: after the Q a-frags are register-resident, sA is
// reused as the second K buffer. Prefetch for kt+1 is issued BEFORE the MFMA+exp
// work of kt, so the compiler's vmcnt(0) drain at the single per-kt barrier
// lands after ~2000 cycles of compute -> near-zero stall (vs. the old
// issue/drain/compute structure with two barriers per kt).
// The diagonal element (row==col) is masked to -inf here, so finalize no longer
// needs to re-read qn/kn to reconstruct it.
__global__ __launch_bounds__(256,2) void simexp_kernel(const unsigned short* __restrict__ qn,
                                                       const unsigned short* __restrict__ kn,
                                                       float* __restrict__ rowsum){
  __shared__ uint4 sA[2048];   // 32 KB: Q tile, then odd-kt K buffer
  __shared__ uint4 sB[2048];   // 32 KB: even-kt K buffer
  int t = threadIdx.x;
  int w = t >> 6, lane = t & 63;
  int quad = lane >> 4, l16 = lane & 15;
  int b  = blockIdx.z;
  int r0 = blockIdx.x * 128;
  int c0 = blockIdx.y * 1024;
  const uint4* gq = reinterpret_cast<const uint4*>(qn + ((size_t)b*NN + r0)*DD);
  const uint4* gk = reinterpret_cast<const uint4*>(kn + ((size_t)b*NN + c0)*DD);
  // stage Q -> sA, K tile 0 -> sB (global data already swizzle-laid-out)
  #pragma unroll
  for (int i = 0; i < 8; ++i)
    async_copy16(gq + w*512 + i*64 + lane, &sA[w*512 + i*64]);
  #pragma unroll
  for (int i = 0; i < 8; ++i)
    async_copy16(gk + w*512 + i*64 + lane, &sB[w*512 + i*64]);
  __syncthreads();

  int wr = (w >> 1)*64, wc = (w & 1)*64;   // wave quadrant
  // a-frags register-resident: rows wr+i*16+l16, k-chunk ks*4+quad (deswizzle by ^l16)
  bf16x8 a[4][4];
  #pragma unroll
  for (int i = 0; i < 4; ++i){
    int row = wr + i*16 + l16;
    #pragma unroll
    for (int ks = 0; ks < 4; ++ks)
      a[i][ks] = __builtin_bit_cast(bf16x8, sA[row*16 + ((ks*4 + quad) ^ l16)]);
  }
  __syncthreads();   // all waves done with sA -> reusable as K prefetch buffer

  float rsum[16];
  #pragma unroll
  for (int s = 0; s < 16; ++s) rsum[s] = 0.f;

  for (int kt = 0; kt < 8; ++kt){
    const uint4* rd  = (kt & 1) ? sA : sB;   // buffer holding K tile kt
    uint4*       wrb = (kt & 1) ? sB : sA;   // destination for K tile kt+1
    if (kt < 7){
      #pragma unroll
      for (int i = 0; i < 8; ++i)
        async_copy16(gk + (kt+1)*2048 + w*512 + i*64 + lane, &wrb[w*512 + i*64]);
    }
    f32x4 acc[4][4];
    #pragma unroll
    for (int i = 0; i < 4; ++i)
      #pragma unroll
      for (int j = 0; j < 4; ++j)
        acc[i][j] = (f32x4){0.f, 0.f, 0.f, 0.f};
    #pragma unroll
    for (int ks = 0; ks < 4; ++ks){
      bf16x8 bfr[4];
      #pragma unroll
      for (int j = 0; j < 4; ++j){
        int col = wc + j*16 + l16;
        bfr[j] = __builtin_bit_cast(bf16x8, rd[col*16 + ((ks*4 + quad) ^ l16)]);
      }
      #pragma unroll
      for (int i = 0; i < 4; ++i)
        #pragma unroll
        for (int j = 0; j < 4; ++j)
          acc[i][j] = __builtin_amdgcn_mfma_f32_16x16x32_bf16(a[i][ks], bfr[j], acc[i][j], 0, 0, 0);
    }
    // mask the diagonal: row == col only possible when this kt's col tile aligns
    // with our row tile (c0+kt*128 == r0), in waves with wr==wc (w==0 or w==3),
    // at i==j, quad==l16>>2, reg r==l16&3. exp2(-1e38*EXP2C) -> exp2(-inf) = 0.
    if ((c0 + kt*128 == r0) && (wr == wc)){
      bool hit = (quad == (l16 >> 2));
      int rr = l16 & 3;
      #pragma unroll
      for (int i = 0; i < 4; ++i)
        #pragma unroll
        for (int r = 0; r < 4; ++r)
          acc[i][i][r] = (hit && r == rr) ? -1e38f : acc[i][i][r];
    }
    // epilogue: C[row=i*16+quad*4+r][col=j*16+l16]; single mul + v_exp per element
    #pragma unroll
    for (int i = 0; i < 4; ++i)
      #pragma unroll
      for (int j = 0; j < 4; ++j)
        #pragma unroll
        for (int r = 0; r < 4; ++r)
          rsum[i*4 + r] += exp2f(acc[i][j][r] * EXP2C);
    __syncthreads();   // drains prefetch (compiler vmcnt(0)) + guards buffer swap
  }
  // reduce over the 16 cols (l16 lanes) per quad, then atomic per row
  #pragma unroll
  for (int s = 0; s < 16; ++s){
    float v = rsum[s];
    v += __shfl_xor(v, 1, 64);
    v += __shfl_xor(v, 2, 64);
    v += __shfl_xor(v, 4, 64);
    v += __shfl_xor(v, 8, 64);
    if (l16 == 0){
      int row = r0 + wr + (s >> 2)*16 + quad*4 + (s & 3);
      atomicAdd(&rowsum[b*NN + row], v);
    }
  }
}

// Kernel C: loss = mean(log1p(rowsum)) — diagonal already excluded in simexp.
__global__ __launch_bounds__(256) void finalize_kernel(const float* __restrict__ rowsum,
                                                       float* __restrict__ out){
  int idx = blockIdx.x*256 + threadIdx.x;   // 0..16383 = b*N + n
  float loss = log1pf(rowsum[idx]);
  loss += __shfl_xor(loss, 1, 64);
  loss += __shfl_xor(loss, 2, 64);
  loss += __shfl_xor(loss, 4, 64);
  loss += __shfl_xor(loss, 8, 64);
  loss += __shfl_xor(loss, 16, 64);
  loss += __shfl_xor(loss, 32, 64);
  if ((threadIdx.x & 63) == 0)
    atomicAdd(out, loss * (1.f / (float)(NB*NN)));
}

extern "C" void kernel_launch(void* const* d_in, const int* in_sizes, int n_in,
                              void* d_out, int out_size, void* d_ws, size_t ws_size,
                              hipStream_t stream){
  const float* fq = (const float*)d_in[0];
  const float* fk = (const float*)d_in[1];
  unsigned short* qn = (unsigned short*)d_ws;                  // 4 MB bf16 [B][N][D] (chunk-swizzled)
  unsigned short* kn = qn + (size_t)NB*NN*DD;                  // 4 MB
  float* rowsum = (float*)(kn + (size_t)NB*NN*DD);             // 64 KB
  float* out = (float*)d_out;

  norm_kernel<<<dim3(NN/64, NB, 2), 256, 0, stream>>>(fq, fk, qn, kn, rowsum, out);
  simexp_kernel<<<dim3(NN/128, 4, NB), 256, 0, stream>>>(qn, kn, rowsum);
  finalize_kernel<<<dim3(NB*NN/256), 256, 0, stream>>>(rowsum, out);
}